// Round 6
// baseline (62.208 us; speedup 1.0000x reference)
//
#include <hip/hip_runtime.h>

// x:(8,64,56,56) f32 -> out:(8,64,49,3136) f32
// out[n,c,ki*7+kj, oh*56+ow] = x[n,c,oh,ow] - (in-bounds ? x[n,c,oh+ki-3,ow+kj-3] : 0)
//
// R5: one block per (n,c) plane (512 blocks, 2/CU). Plane staged in LDS with
// zero halo, pitch 68 (16B-aligned rows; 68%32=4 -> 4-bank row rotation).
// Halo: 4 cols left, 8 right, 3 rows top/bottom. Per (slot,ki) the neighbor
// window [ow-4 .. ow+7+4] is 3 aligned ds_read_b128; all 7 kj shifts are
// compile-time register selects. Tail slot (16 threads) merged/predicated.
// Stores: ki-major -> each block writes its 614 KB region front-to-back.

constexpr int H_ = 56, W_ = 56;
constexpr int KK_  = 49;
constexpr int OHW_ = 3136;
constexpr int NC_  = 512;
constexpr int PITCH = 68;              // dwords/row, 16B aligned
constexpr int PROWS = 62;              // rows -3..58
constexpr int LHALO = 4;               // left halo cols (need 3, +1 alignment)
constexpr int LDSF  = PROWS * PITCH;   // 4216 floats = 16.9 KB
constexpr int LDS4  = LDSF / 4;        // 1054 f32x4

typedef float f32x4 __attribute__((ext_vector_type(4)));

// select window element j (0..11) from three quads (compile-time j after unroll)
#define WSEL(A, B, C, J) ((J) < 4 ? (A)[(J) & 3] : ((J) < 8 ? (B)[(J) & 3] : (C)[(J) & 3]))

__global__ __launch_bounds__(256)
void san_kernel(const float* __restrict__ x, float* __restrict__ out) {
    __shared__ f32x4 lds4[LDS4];
    float* lds = reinterpret_cast<float*>(lds4);
    const int nc = blockIdx.x;
    const int t  = threadIdx.x;

    // 1) zero padded plane (halo -> OOB neighbors read 0)
    #pragma unroll
    for (int i = 0; i < 5; ++i) {
        int j = t + 256 * i;
        if (j < LDS4) lds4[j] = f32x4{0.f, 0.f, 0.f, 0.f};
    }
    __syncthreads();

    const float* plane = x + (size_t)nc * OHW_;

    // 2) stage interior (aligned b128 ds_writes); keep centers in registers.
    //    slot S covers plane f4-index e4 = t + 256*S (784 total; slot3: t<16)
    f32x4 cen0{}, cen1{}, cen2{}, cen3{};
    int rb0 = 0, rb1 = 0, rb2 = 0, rb3 = 0;   // window base: row oh, col ow-4 (padded)
    const bool has3 = (t < 16);

#define STAGE(S, CEN, RB)                                            \
    {                                                                \
        int e4 = t + 256 * (S);                                      \
        int oh = e4 / 14, o4 = e4 - oh * 14;                         \
        CEN = *reinterpret_cast<const f32x4*>(plane + e4 * 4);       \
        int lb = (oh + 3) * PITCH + LHALO + o4 * 4;                  \
        *reinterpret_cast<f32x4*>(lds + lb) = CEN;                   \
        RB = oh * PITCH + (LHALO - 4) + o4 * 4;                      \
    }
    STAGE(0, cen0, rb0)
    STAGE(1, cen1, rb1)
    STAGE(2, cen2, rb2)
    if (has3) STAGE(3, cen3, rb3)
#undef STAGE
    __syncthreads();

    // 3) ki-major sweep; per (slot,ki): 3 aligned b128 LDS reads, then 7 kj
    //    from registers. Block writes 7 consecutive output slices per ki.
    float* ob  = out + (size_t)nc * (KK_ * OHW_);
    float* op0 = ob + (size_t)(t      ) * 4;
    float* op1 = ob + (size_t)(t + 256) * 4;
    float* op2 = ob + (size_t)(t + 512) * 4;
    float* op3 = ob + (size_t)(t + 768) * 4;   // used only if has3

    #pragma unroll
    for (int ki = 0; ki < 7; ++ki) {
        const float* w0 = lds + rb0 + ki * PITCH;
        const float* w1 = lds + rb1 + ki * PITCH;
        const float* w2 = lds + rb2 + ki * PITCH;
        const float* w3 = lds + rb3 + ki * PITCH;
        f32x4 a0 = *(const f32x4*)(w0), b0 = *(const f32x4*)(w0 + 4), c0 = *(const f32x4*)(w0 + 8);
        f32x4 a1 = *(const f32x4*)(w1), b1 = *(const f32x4*)(w1 + 4), c1 = *(const f32x4*)(w1 + 8);
        f32x4 a2 = *(const f32x4*)(w2), b2 = *(const f32x4*)(w2 + 4), c2 = *(const f32x4*)(w2 + 8);
        f32x4 a3{}, b3{}, c3{};
        if (has3) { a3 = *(const f32x4*)(w3); b3 = *(const f32x4*)(w3 + 4); c3 = *(const f32x4*)(w3 + 8); }

        #pragma unroll
        for (int kj = 0; kj < 7; ++kj) {
            // neighbor col ow+kj-3+tt -> window element j = kj+1+tt (1..10)
            f32x4 r0, r1, r2, r3;
            #pragma unroll
            for (int tt = 0; tt < 4; ++tt) {
                r0[tt] = cen0[tt] - WSEL(a0, b0, c0, kj + 1 + tt);
                r1[tt] = cen1[tt] - WSEL(a1, b1, c1, kj + 1 + tt);
                r2[tt] = cen2[tt] - WSEL(a2, b2, c2, kj + 1 + tt);
                r3[tt] = cen3[tt] - WSEL(a3, b3, c3, kj + 1 + tt);
            }
            *reinterpret_cast<f32x4*>(op0) = r0;  op0 += OHW_;
            *reinterpret_cast<f32x4*>(op1) = r1;  op1 += OHW_;
            *reinterpret_cast<f32x4*>(op2) = r2;  op2 += OHW_;
            if (has3) *reinterpret_cast<f32x4*>(op3) = r3;
            op3 += OHW_;
        }
    }
}

extern "C" void kernel_launch(void* const* d_in, const int* in_sizes, int n_in,
                              void* d_out, int out_size, void* d_ws, size_t ws_size,
                              hipStream_t stream) {
    const float* x = (const float*)d_in[0];
    float* out = (float*)d_out;
    san_kernel<<<NC_, 256, 0, stream>>>(x, out);
}

// Round 7
// 57.630 us; speedup vs baseline: 1.0794x; 1.0794x over previous
//
#include <hip/hip_runtime.h>

// x:(8,64,56,56) f32 -> out:(8,64,49,3136) f32
// out[n,c,ki*7+kj, oh*56+ow] = x[n,c,oh,ow] - (in-bounds ? x[n,c,oh+ki-3,ow+kj-3] : 0)
//
// R6: one block per (nc, ki): 3584 blocks (~8 resident/CU vs R4's 2).
// Keeps R4's LDS layout (pitch 63, zero halo) and scalar ds_reads, but with
// ki fixed per block each slot needs only lds[base .. base+9] (10 contiguous
// floats -> ds_read2_b32 pairs). Block writes 7 consecutive output slices
// (87.8 KB contiguous, bid-ordered) -> DRAM-sequential like R4, with enough
// resident blocks to hide the staging prologue and absorb the has3 tail.

constexpr int H_ = 56, W_ = 56;
constexpr int KK_  = 49;
constexpr int OHW_ = 3136;
constexpr int PP_  = 63;               // LDS pitch (floats)
constexpr int PR_  = 62;               // padded rows -3..58
constexpr int NC_  = 512;              // 8*64 planes
constexpr int LDSN_ = PR_ * PP_;       // 3906 floats = 15.6 KB

typedef float f32x4 __attribute__((ext_vector_type(4)));

__global__ __launch_bounds__(256)
void san_kernel(const float* __restrict__ x, float* __restrict__ out) {
    __shared__ float lds[LDSN_];
    const int bid = blockIdx.x;
    const int nc  = bid / 7;
    const int ki  = bid - nc * 7;      // this block's kernel row
    const int t   = threadIdx.x;

    // 1) zero padded plane (halo stays zero -> OOB neighbors read 0)
    #pragma unroll
    for (int i = 0; i < 16; ++i) {
        int j = t + 256 * i;
        if (j < LDSN_) lds[j] = 0.0f;
    }
    __syncthreads();

    const float* plane = x + (size_t)nc * OHW_;

    // 2) stage interior; keep each slot's center f4 + LDS window base.
    //    slot S covers f4-index e4 = t + 256*S (784 total; slot3: t<16 only)
    f32x4 cen0{}, cen1{}, cen2{}, cen3{};
    int wb0 = 0, wb1 = 0, wb2 = 0, wb3 = 0;
    const bool has3 = (t < 16);
    const int kio = ki * PP_;          // uniform

#define STAGE(S, CEN, WB)                                           \
    {                                                               \
        int e4 = t + 256 * (S);                                     \
        int oh = e4 / 14, o4 = e4 - oh * 14;                        \
        CEN = *reinterpret_cast<const f32x4*>(plane + e4 * 4);      \
        int lb = (oh + 3) * PP_ + o4 * 4 + 3;                       \
        lds[lb + 0] = CEN[0]; lds[lb + 1] = CEN[1];                 \
        lds[lb + 2] = CEN[2]; lds[lb + 3] = CEN[3];                 \
        WB = oh * PP_ + o4 * 4 + kio;                               \
    }
    STAGE(0, cen0, wb0)
    STAGE(1, cen1, wb1)
    STAGE(2, cen2, wb2)
    if (has3) STAGE(3, cen3, wb3)
#undef STAGE
    __syncthreads();

    // 3) load each slot's 10-float neighbor window (contiguous -> ds_read2),
    //    then emit 7 kj slices; block region = 7*12544 B written in order.
    float w0[10], w1[10], w2[10], w3[10];
    #pragma unroll
    for (int j = 0; j < 10; ++j) {
        w0[j] = lds[wb0 + j];
        w1[j] = lds[wb1 + j];
        w2[j] = lds[wb2 + j];
        w3[j] = has3 ? lds[wb3 + j] : 0.0f;
    }

    float* ob  = out + (size_t)nc * (KK_ * OHW_) + (size_t)(ki * 7) * OHW_;
    float* op0 = ob + (size_t)(t      ) * 4;
    float* op1 = ob + (size_t)(t + 256) * 4;
    float* op2 = ob + (size_t)(t + 512) * 4;
    float* op3 = ob + (size_t)(t + 768) * 4;   // only stored if has3

    #pragma unroll
    for (int kj = 0; kj < 7; ++kj) {
        f32x4 r0, r1, r2, r3;
        #pragma unroll
        for (int tt = 0; tt < 4; ++tt) {
            r0[tt] = cen0[tt] - w0[kj + tt];
            r1[tt] = cen1[tt] - w1[kj + tt];
            r2[tt] = cen2[tt] - w2[kj + tt];
            r3[tt] = cen3[tt] - w3[kj + tt];
        }
        *reinterpret_cast<f32x4*>(op0) = r0;  op0 += OHW_;
        *reinterpret_cast<f32x4*>(op1) = r1;  op1 += OHW_;
        *reinterpret_cast<f32x4*>(op2) = r2;  op2 += OHW_;
        if (has3) *reinterpret_cast<f32x4*>(op3) = r3;
        op3 += OHW_;
    }
}

extern "C" void kernel_launch(void* const* d_in, const int* in_sizes, int n_in,
                              void* d_out, int out_size, void* d_ws, size_t ws_size,
                              hipStream_t stream) {
    const float* x = (const float*)d_in[0];
    float* out = (float*)d_out;
    san_kernel<<<NC_ * 7, 256, 0, stream>>>(x, out);
}